// Round 1
// baseline (466.789 us; speedup 1.0000x reference)
//
#include <hip/hip_runtime.h>
#include <hip/hip_bf16.h>

// Problem constants
#define BB 64
#define NN 4096
#define DD 64
#define HH 256
#define SS 1024
#define TOTAL 49152          // 3*D*H
#define MAT_ELEMS 16384      // D*H

typedef __bf16 bf16x8 __attribute__((ext_vector_type(8)));
typedef float  f32x4  __attribute__((ext_vector_type(4)));

// ---------------------------------------------------------------------------
// K1: params[64][49152] = s[64][1024] @ W_pg[1024][49152] + b_pg
// Register-tiled fp32 vector GEMM. Tile: M=64 (all rows) x N=64, K-chunks of 32.
// grid 768, block 256 (16x16 threads, each 4x4 outputs).
// ---------------------------------------------------------------------------
__global__ __launch_bounds__(256, 4) void k1_gemm(
    const float* __restrict__ s, const float* __restrict__ W,
    const float* __restrict__ bias, float* __restrict__ params)
{
    const int n0 = blockIdx.x * 64;
    const int t  = threadIdx.x;
    const int tx = t & 15, ty = t >> 4;

    __shared__ float sA[64 * 36];   // s tile [m][kk], pad 36 keeps float4 align
    __shared__ float sB[32 * 68];   // W tile [kk][n], pad 68 keeps float4 align

    float acc[4][4] = {};

    for (int k0 = 0; k0 < SS; k0 += 32) {
        // load sA: 64x32 floats = 512 float4, 2 per thread
        #pragma unroll
        for (int i = 0; i < 2; i++) {
            int f4i = t + i * 256;
            int m = f4i >> 3, k4 = f4i & 7;
            float4 v = *(const float4*)&s[m * SS + k0 + k4 * 4];
            *(float4*)&sA[m * 36 + k4 * 4] = v;
        }
        // load sB: 32x64 floats = 512 float4, 2 per thread
        #pragma unroll
        for (int i = 0; i < 2; i++) {
            int f4i = t + i * 256;
            int kk = f4i >> 4, n4 = f4i & 15;
            float4 v = *(const float4*)&W[(size_t)(k0 + kk) * TOTAL + n0 + n4 * 4];
            *(float4*)&sB[kk * 68 + n4 * 4] = v;
        }
        __syncthreads();
        #pragma unroll
        for (int kk = 0; kk < 32; kk++) {
            float4 b = *(const float4*)&sB[kk * 68 + tx * 4];
            float a0 = sA[(ty * 4 + 0) * 36 + kk];
            float a1 = sA[(ty * 4 + 1) * 36 + kk];
            float a2 = sA[(ty * 4 + 2) * 36 + kk];
            float a3 = sA[(ty * 4 + 3) * 36 + kk];
            acc[0][0] += a0 * b.x; acc[0][1] += a0 * b.y; acc[0][2] += a0 * b.z; acc[0][3] += a0 * b.w;
            acc[1][0] += a1 * b.x; acc[1][1] += a1 * b.y; acc[1][2] += a1 * b.z; acc[1][3] += a1 * b.w;
            acc[2][0] += a2 * b.x; acc[2][1] += a2 * b.y; acc[2][2] += a2 * b.z; acc[2][3] += a2 * b.w;
            acc[3][0] += a3 * b.x; acc[3][1] += a3 * b.y; acc[3][2] += a3 * b.z; acc[3][3] += a3 * b.w;
        }
        __syncthreads();
    }

    #pragma unroll
    for (int r = 0; r < 4; r++) {
        int m = ty * 4 + r;
        int n = n0 + tx * 4;
        float4 bv = *(const float4*)&bias[n];
        float4 o;
        o.x = acc[r][0] + bv.x; o.y = acc[r][1] + bv.y;
        o.z = acc[r][2] + bv.z; o.w = acc[r][3] + bv.w;
        *(float4*)&params[(size_t)m * TOTAL + n] = o;
    }
}

// ---------------------------------------------------------------------------
// K2a: fc1 gate/value l2norm along D, write transposed bf16 WT[h][d].
// grid 128 (64 batches x {g,v}), block 256.
// ---------------------------------------------------------------------------
__global__ __launch_bounds__(256) void k2_fc1(
    const float* __restrict__ params, __bf16* __restrict__ WgT, __bf16* __restrict__ WvT)
{
    const int b   = blockIdx.x >> 1;
    const int mat = blockIdx.x & 1;
    const int t   = threadIdx.x;
    __shared__ float sh[64 * 257];     // [d][h], pad 257
    __shared__ float rnorm[HH];

    const float* src = params + (size_t)b * TOTAL + mat * MAT_ELEMS;
    #pragma unroll
    for (int i = 0; i < 64; i++) {
        int idx = t + i * 256;          // idx = d*256 + h
        int d = idx >> 8, h = idx & 255;
        sh[d * 257 + h] = src[idx];
    }
    __syncthreads();
    // thread t handles h = t: norm over d (stride-257 reads, 2-way banks = free)
    {
        float sum = 0.f;
        #pragma unroll
        for (int d = 0; d < 64; d++) {
            float v = sh[d * 257 + t];
            sum += v * v;
        }
        rnorm[t] = 1.0f / fmaxf(sqrtf(sum), 1e-12f);
    }
    __syncthreads();
    __bf16* dst = (mat ? WvT : WgT) + (size_t)b * MAT_ELEMS;
    #pragma unroll
    for (int i = 0; i < 64; i++) {
        int idx = t + i * 256;          // out flat = h*64 + d
        int h = idx >> 6, d = idx & 63;
        dst[idx] = (__bf16)(sh[d * 257 + h] * rnorm[h]);
    }
}

// ---------------------------------------------------------------------------
// K2b: fc2 l2norm along H, write transposed bf16 WfT[d][h]. grid 64, block 256.
// ---------------------------------------------------------------------------
__global__ __launch_bounds__(256) void k2_fc2(
    const float* __restrict__ params, __bf16* __restrict__ WfT)
{
    const int b = blockIdx.x;
    const int t = threadIdx.x;
    __shared__ float sh[256 * 65];     // [h][d], pad 65
    __shared__ float psum[4 * 64];
    __shared__ float rnorm[DD];

    const float* src = params + (size_t)b * TOTAL + 2 * MAT_ELEMS;
    #pragma unroll
    for (int i = 0; i < 64; i++) {
        int idx = t + i * 256;          // idx = h*64 + d
        int h = idx >> 6, d = idx & 63;
        sh[h * 65 + d] = src[idx];
    }
    __syncthreads();
    {
        int d = t & 63, q = t >> 6;
        float sum = 0.f;
        #pragma unroll
        for (int i = 0; i < 64; i++) {
            int h = q * 64 + i;
            float v = sh[h * 65 + d];
            sum += v * v;
        }
        psum[q * 64 + d] = sum;
    }
    __syncthreads();
    if (t < 64) {
        float sum = psum[t] + psum[64 + t] + psum[128 + t] + psum[192 + t];
        rnorm[t] = 1.0f / fmaxf(sqrtf(sum), 1e-12f);
    }
    __syncthreads();
    __bf16* dst = WfT + (size_t)b * MAT_ELEMS;
    #pragma unroll
    for (int i = 0; i < 64; i++) {
        int idx = t + i * 256;          // out flat = d*256 + h
        int d = idx >> 8, h = idx & 255;
        dst[idx] = (__bf16)(sh[h * 65 + d] * rnorm[d]);
    }
}

// ---------------------------------------------------------------------------
// K3: fused  xn = rmsnorm(x)*scale;  g = xn@Wg; v = xn@Wv; h = silu(g)*v;
//            out = h@Wf + x.
// grid 1024 (64 batches x 16 row-blocks of 256 rows), block 256 = 4 waves.
// Each wave owns 64 rows (4 m-tiles); everything is wave-private: NO barriers.
// MFMA 16x16x32 bf16. Weight B-frags stream from global (L2-resident/batch).
// ---------------------------------------------------------------------------
__global__ __launch_bounds__(256, 2) void k3_fused(
    const float* __restrict__ x, const float* __restrict__ scale,
    const __bf16* __restrict__ WgT, const __bf16* __restrict__ WvT,
    const __bf16* __restrict__ WfT, float* __restrict__ out)
{
    const int b    = blockIdx.x >> 4;
    const int rb   = blockIdx.x & 15;
    const int t    = threadIdx.x;
    const int w    = t >> 6;
    const int lane = t & 63;
    const int l15  = lane & 15;
    const int quad = lane >> 4;

    __shared__ __bf16 xn_sh[256 * 72];      // [row][d], rows padded to 72 bf16
    __shared__ __bf16 h_sh[4 * 64 * 40];    // per-wave [64 rows][32 h] pad 40

    const size_t row_base = ((size_t)b * NN + rb * 256) * DD;

    // ---- phase 0: RMSNorm 64 rows per wave -> bf16 LDS (wave-private) ----
    const float scl = scale[lane];
    for (int r = 0; r < 64; r++) {
        int row = w * 64 + r;
        float v = x[row_base + (size_t)row * DD + lane];
        float ss = v * v;
        #pragma unroll
        for (int off = 32; off; off >>= 1) ss += __shfl_xor(ss, off, 64);
        float rr = rsqrtf(ss * (1.0f / 64.0f) + 1e-6f);
        xn_sh[row * 72 + lane] = (__bf16)(v * rr * scl);
    }

    // ---- preload A-fragments: A[m][k], lane m=l15, k=quad*8+j (+32*ks) ----
    bf16x8 afrag[4][2];
    #pragma unroll
    for (int mt = 0; mt < 4; mt++)
        #pragma unroll
        for (int ks = 0; ks < 2; ks++)
            afrag[mt][ks] = *(const bf16x8*)&xn_sh[(w * 64 + mt * 16 + l15) * 72 + ks * 32 + quad * 8];

    f32x4 oacc[4][4] = {};   // [mt][dt]
    const __bf16* wg_b = WgT + (size_t)b * MAT_ELEMS;
    const __bf16* wv_b = WvT + (size_t)b * MAT_ELEMS;
    const __bf16* wf_b = WfT + (size_t)b * MAT_ELEMS;
    __bf16* hbuf = &h_sh[w * 64 * 40];

    for (int np = 0; np < 8; np++) {
        // ---- fc1 pair: two n-tiles of 16 h-columns each ----
        #pragma unroll
        for (int sub = 0; sub < 2; sub++) {
            int nt = np * 2 + sub;
            const __bf16* gp = &wg_b[(nt * 16 + l15) * 64 + quad * 8];
            const __bf16* vp = &wv_b[(nt * 16 + l15) * 64 + quad * 8];
            bf16x8 bg0 = *(const bf16x8*)(gp);
            bf16x8 bg1 = *(const bf16x8*)(gp + 32);
            bf16x8 bv0 = *(const bf16x8*)(vp);
            bf16x8 bv1 = *(const bf16x8*)(vp + 32);
            #pragma unroll
            for (int mt = 0; mt < 4; mt++) {
                f32x4 g = {0.f, 0.f, 0.f, 0.f}, vv = {0.f, 0.f, 0.f, 0.f};
                g  = __builtin_amdgcn_mfma_f32_16x16x32_bf16(afrag[mt][0], bg0, g, 0, 0, 0);
                g  = __builtin_amdgcn_mfma_f32_16x16x32_bf16(afrag[mt][1], bg1, g, 0, 0, 0);
                vv = __builtin_amdgcn_mfma_f32_16x16x32_bf16(afrag[mt][0], bv0, vv, 0, 0, 0);
                vv = __builtin_amdgcn_mfma_f32_16x16x32_bf16(afrag[mt][1], bv1, vv, 0, 0, 0);
                // silu(g)*v -> bf16 -> wave-private LDS (C-layout scatter)
                #pragma unroll
                for (int r = 0; r < 4; r++) {
                    float gv = g[r];
                    float hval = (gv / (1.0f + __expf(-gv))) * vv[r];
                    hbuf[(mt * 16 + quad * 4 + r) * 40 + sub * 16 + l15] = (__bf16)hval;
                }
            }
        }
        // ---- fc2 partial over k_h = np*32..np*32+31 ----
        bf16x8 bff[4];
        #pragma unroll
        for (int dt = 0; dt < 4; dt++)
            bff[dt] = *(const bf16x8*)&wf_b[(dt * 16 + l15) * 256 + np * 32 + quad * 8];
        #pragma unroll
        for (int mt = 0; mt < 4; mt++) {
            bf16x8 ah = *(const bf16x8*)&hbuf[(mt * 16 + l15) * 40 + quad * 8];
            #pragma unroll
            for (int dt = 0; dt < 4; dt++)
                oacc[mt][dt] = __builtin_amdgcn_mfma_f32_16x16x32_bf16(ah, bff[dt], oacc[mt][dt], 0, 0, 0);
        }
    }

    // ---- epilogue: += x residual, store fp32 (C-layout) ----
    #pragma unroll
    for (int mt = 0; mt < 4; mt++) {
        int r0 = w * 64 + mt * 16 + quad * 4;
        #pragma unroll
        for (int rg = 0; rg < 4; rg++) {
            size_t roff = row_base + (size_t)(r0 + rg) * DD;
            #pragma unroll
            for (int dt = 0; dt < 4; dt++) {
                int col = dt * 16 + l15;
                out[roff + col] = oacc[mt][dt][rg] + x[roff + col];
            }
        }
    }
}

// ---------------------------------------------------------------------------
extern "C" void kernel_launch(void* const* d_in, const int* in_sizes, int n_in,
                              void* d_out, int out_size, void* d_ws, size_t ws_size,
                              hipStream_t stream)
{
    const float* x     = (const float*)d_in[0];
    const float* s     = (const float*)d_in[1];
    const float* W_pg  = (const float*)d_in[2];
    const float* b_pg  = (const float*)d_in[3];
    const float* scale = (const float*)d_in[4];
    float* out = (float*)d_out;

    char* ws = (char*)d_ws;
    float*  params = (float*)ws;                                  // 12,582,912 B
    __bf16* WgT    = (__bf16*)(ws + 12582912);                    //  2,097,152 B
    __bf16* WvT    = (__bf16*)(ws + 14680064);                    //  2,097,152 B
    __bf16* WfT    = (__bf16*)(ws + 16777216);                    //  2,097,152 B

    k1_gemm<<<TOTAL / 64, 256, 0, stream>>>(s, W_pg, b_pg, params);
    k2_fc1<<<BB * 2, 256, 0, stream>>>(params, WgT, WvT);
    k2_fc2<<<BB, 256, 0, stream>>>(params, WfT);
    k3_fused<<<BB * 16, 256, 0, stream>>>(x, scale, WgT, WvT, WfT, out);
}

// Round 2
// 457.032 us; speedup vs baseline: 1.0213x; 1.0213x over previous
//
#include <hip/hip_runtime.h>
#include <hip/hip_bf16.h>

// Problem constants
#define BB 64
#define NN 4096
#define DD 64
#define HH 256
#define SS 1024
#define TOTAL 49152          // 3*D*H
#define MAT_ELEMS 16384      // D*H

typedef __bf16 bf16x8 __attribute__((ext_vector_type(8)));
typedef float  f32x4  __attribute__((ext_vector_type(4)));

// ---------------------------------------------------------------------------
// K1: params[64][49152] = s[64][1024] @ W_pg[1024][49152] + b_pg
// Register-tiled fp32 vector GEMM. Tile: M=64 (all rows) x N=64, K-chunks of 32.
// grid 768, block 256 (16x16 threads, each 4x4 outputs). (unchanged from R1)
// ---------------------------------------------------------------------------
__global__ __launch_bounds__(256, 4) void k1_gemm(
    const float* __restrict__ s, const float* __restrict__ W,
    const float* __restrict__ bias, float* __restrict__ params)
{
    const int n0 = blockIdx.x * 64;
    const int t  = threadIdx.x;
    const int tx = t & 15, ty = t >> 4;

    __shared__ float sA[64 * 36];   // s tile [m][kk]
    __shared__ float sB[32 * 68];   // W tile [kk][n]

    float acc[4][4] = {};

    for (int k0 = 0; k0 < SS; k0 += 32) {
        #pragma unroll
        for (int i = 0; i < 2; i++) {
            int f4i = t + i * 256;
            int m = f4i >> 3, k4 = f4i & 7;
            float4 v = *(const float4*)&s[m * SS + k0 + k4 * 4];
            *(float4*)&sA[m * 36 + k4 * 4] = v;
        }
        #pragma unroll
        for (int i = 0; i < 2; i++) {
            int f4i = t + i * 256;
            int kk = f4i >> 4, n4 = f4i & 15;
            float4 v = *(const float4*)&W[(size_t)(k0 + kk) * TOTAL + n0 + n4 * 4];
            *(float4*)&sB[kk * 68 + n4 * 4] = v;
        }
        __syncthreads();
        #pragma unroll
        for (int kk = 0; kk < 32; kk++) {
            float4 b = *(const float4*)&sB[kk * 68 + tx * 4];
            float a0 = sA[(ty * 4 + 0) * 36 + kk];
            float a1 = sA[(ty * 4 + 1) * 36 + kk];
            float a2 = sA[(ty * 4 + 2) * 36 + kk];
            float a3 = sA[(ty * 4 + 3) * 36 + kk];
            acc[0][0] += a0 * b.x; acc[0][1] += a0 * b.y; acc[0][2] += a0 * b.z; acc[0][3] += a0 * b.w;
            acc[1][0] += a1 * b.x; acc[1][1] += a1 * b.y; acc[1][2] += a1 * b.z; acc[1][3] += a1 * b.w;
            acc[2][0] += a2 * b.x; acc[2][1] += a2 * b.y; acc[2][2] += a2 * b.z; acc[2][3] += a2 * b.w;
            acc[3][0] += a3 * b.x; acc[3][1] += a3 * b.y; acc[3][2] += a3 * b.z; acc[3][3] += a3 * b.w;
        }
        __syncthreads();
    }

    #pragma unroll
    for (int r = 0; r < 4; r++) {
        int m = ty * 4 + r;
        int n = n0 + tx * 4;
        float4 bv = *(const float4*)&bias[n];
        float4 o;
        o.x = acc[r][0] + bv.x; o.y = acc[r][1] + bv.y;
        o.z = acc[r][2] + bv.z; o.w = acc[r][3] + bv.w;
        *(float4*)&params[(size_t)m * TOTAL + n] = o;
    }
}

// ---------------------------------------------------------------------------
// K2a: fc1 gate/value l2norm along D, write transposed bf16 WT[h][d].
// grid 256 (64 b x {g,v} x 2 h-halves), block 256.
// ---------------------------------------------------------------------------
__global__ __launch_bounds__(256) void k2_fc1(
    const float* __restrict__ params, __bf16* __restrict__ WgT, __bf16* __restrict__ WvT)
{
    const int b   = blockIdx.x >> 2;
    const int mat = (blockIdx.x >> 1) & 1;
    const int hh  = blockIdx.x & 1;
    const int t   = threadIdx.x;
    __shared__ float sh[64 * 130];     // [d][h-half 128], pad 130
    __shared__ float rnorm[128];

    const float* src = params + (size_t)b * TOTAL + mat * MAT_ELEMS + hh * 128;
    #pragma unroll
    for (int i = 0; i < 32; i++) {
        int idx = t + i * 256;          // idx = d*128 + h
        int d = idx >> 7, h = idx & 127;
        sh[d * 130 + h] = src[d * 256 + h];
    }
    __syncthreads();
    if (t < 128) {
        float sum = 0.f;
        #pragma unroll
        for (int d = 0; d < 64; d++) {
            float v = sh[d * 130 + t];
            sum += v * v;
        }
        rnorm[t] = 1.0f / fmaxf(sqrtf(sum), 1e-12f);
    }
    __syncthreads();
    __bf16* dst = (mat ? WvT : WgT) + (size_t)b * MAT_ELEMS;
    #pragma unroll
    for (int i = 0; i < 32; i++) {
        int idx = t + i * 256;          // idx = hl*64 + d
        int hl = idx >> 6, d = idx & 63;
        dst[(hh * 128 + hl) * 64 + d] = (__bf16)(sh[d * 130 + hl] * rnorm[hl]);
    }
}

// ---------------------------------------------------------------------------
// K2b: fc2 l2norm along H, write transposed bf16 WfT[d][h].
// grid 128 (64 b x 2 d-halves), block 256.
// ---------------------------------------------------------------------------
__global__ __launch_bounds__(256) void k2_fc2(
    const float* __restrict__ params, __bf16* __restrict__ WfT)
{
    const int b  = blockIdx.x >> 1;
    const int dh = blockIdx.x & 1;
    const int t  = threadIdx.x;
    __shared__ float sh[256 * 33];     // [h][d-half 32], pad 33
    __shared__ float psum[8 * 32];
    __shared__ float rnorm[32];

    const float* src = params + (size_t)b * TOTAL + 2 * MAT_ELEMS + dh * 32;
    #pragma unroll
    for (int i = 0; i < 32; i++) {
        int idx = t + i * 256;          // idx = h*32 + d
        int h = idx >> 5, d = idx & 31;
        sh[h * 33 + d] = src[h * 64 + d];
    }
    __syncthreads();
    {
        int d = t & 31, seg = t >> 5;
        float sum = 0.f;
        #pragma unroll
        for (int hi = 0; hi < 32; hi++) {
            float v = sh[(seg * 32 + hi) * 33 + d];
            sum += v * v;
        }
        psum[seg * 32 + d] = sum;
    }
    __syncthreads();
    if (t < 32) {
        float sum = 0.f;
        #pragma unroll
        for (int seg = 0; seg < 8; seg++) sum += psum[seg * 32 + t];
        rnorm[t] = 1.0f / fmaxf(sqrtf(sum), 1e-12f);
    }
    __syncthreads();
    __bf16* dst = WfT + (size_t)b * MAT_ELEMS;
    #pragma unroll
    for (int i = 0; i < 32; i++) {
        int idx = t + i * 256;          // idx = d*256 + h
        int d = idx >> 8, h = idx & 255;
        dst[(dh * 32 + d) * 256 + h] = (__bf16)(sh[h * 33 + d] * rnorm[d]);
    }
}

// ---------------------------------------------------------------------------
// K3: fused  xn = rmsnorm(x)*scale;  g = xn@Wg; v = xn@Wv; h = silu(g)*v;
//            out = h@Wf + x.
// grid 2048 (64 batches x 32 row-blocks of 128 rows), block 256 = 4 waves.
// Each wave owns 32 rows (2 m-tiles). A-fragments are built DIRECTLY from
// global x (no LDS staging): quad q of a row loads k in [8q,8q+8)+[32+8q,..),
// sumsq reduced across quads with 2 shuffles. Wave-private LDS only for the
// h C-layout -> A-layout roundtrip (9 KB total). NO __syncthreads().
// All 12 weight B-fragments of an np-iteration are issued before any compute.
// ---------------------------------------------------------------------------
__global__ __launch_bounds__(256, 4) void k3_fused(
    const float* __restrict__ x, const float* __restrict__ scale,
    const __bf16* __restrict__ WgT, const __bf16* __restrict__ WvT,
    const __bf16* __restrict__ WfT, float* __restrict__ out)
{
    const int b    = blockIdx.x >> 5;
    const int rb   = blockIdx.x & 31;
    const int t    = threadIdx.x;
    const int w    = t >> 6;
    const int lane = t & 63;
    const int l15  = lane & 15;
    const int quad = lane >> 4;

    __shared__ __bf16 h_sh[4 * 32 * 36];    // per-wave [32 rows][32 h] pad 36

    const size_t row_base = ((size_t)b * NN + rb * 128) * DD;

    // per-lane scale slices for k = quad*8+j and 32+quad*8+j
    float sc[16];
    *(float4*)&sc[0]  = *(const float4*)&scale[quad * 8];
    *(float4*)&sc[4]  = *(const float4*)&scale[quad * 8 + 4];
    *(float4*)&sc[8]  = *(const float4*)&scale[32 + quad * 8];
    *(float4*)&sc[12] = *(const float4*)&scale[32 + quad * 8 + 4];

    // ---- phase 0: build A-fragments straight from global ----
    bf16x8 afrag[2][2];
    #pragma unroll
    for (int mt = 0; mt < 2; mt++) {
        int row = w * 32 + mt * 16 + l15;
        const float* xp = &x[row_base + (size_t)row * DD + quad * 8];
        float v[16];
        *(float4*)&v[0]  = *(const float4*)(xp);
        *(float4*)&v[4]  = *(const float4*)(xp + 4);
        *(float4*)&v[8]  = *(const float4*)(xp + 32);
        *(float4*)&v[12] = *(const float4*)(xp + 36);
        float ss = 0.f;
        #pragma unroll
        for (int j = 0; j < 16; j++) ss += v[j] * v[j];
        ss += __shfl_xor(ss, 16, 64);
        ss += __shfl_xor(ss, 32, 64);
        float rr = rsqrtf(ss * (1.0f / 64.0f) + 1e-6f);
        #pragma unroll
        for (int j = 0; j < 8; j++) {
            afrag[mt][0][j] = (__bf16)(v[j] * rr * sc[j]);
            afrag[mt][1][j] = (__bf16)(v[8 + j] * rr * sc[8 + j]);
        }
    }

    f32x4 oacc[2][4] = {};   // [mt][dt]
    const __bf16* wg_b = WgT + (size_t)b * MAT_ELEMS;
    const __bf16* wv_b = WvT + (size_t)b * MAT_ELEMS;
    const __bf16* wf_b = WfT + (size_t)b * MAT_ELEMS;
    __bf16* hbuf = &h_sh[w * 32 * 36];

    for (int np = 0; np < 8; np++) {
        // ---- issue ALL 12 weight fragment loads for this iteration ----
        bf16x8 bg[2][2], bv[2][2], bf[4];
        #pragma unroll
        for (int sub = 0; sub < 2; sub++) {
            int nt = np * 2 + sub;
            const __bf16* gp = &wg_b[(nt * 16 + l15) * 64 + quad * 8];
            const __bf16* vp = &wv_b[(nt * 16 + l15) * 64 + quad * 8];
            bg[sub][0] = *(const bf16x8*)(gp);
            bg[sub][1] = *(const bf16x8*)(gp + 32);
            bv[sub][0] = *(const bf16x8*)(vp);
            bv[sub][1] = *(const bf16x8*)(vp + 32);
        }
        #pragma unroll
        for (int dt = 0; dt < 4; dt++)
            bf[dt] = *(const bf16x8*)&wf_b[(dt * 16 + l15) * 256 + np * 32 + quad * 8];

        // ---- fc1 pair + silu -> wave-private LDS ----
        #pragma unroll
        for (int sub = 0; sub < 2; sub++) {
            #pragma unroll
            for (int mt = 0; mt < 2; mt++) {
                f32x4 g = {0.f, 0.f, 0.f, 0.f}, vv = {0.f, 0.f, 0.f, 0.f};
                g  = __builtin_amdgcn_mfma_f32_16x16x32_bf16(afrag[mt][0], bg[sub][0], g, 0, 0, 0);
                g  = __builtin_amdgcn_mfma_f32_16x16x32_bf16(afrag[mt][1], bg[sub][1], g, 0, 0, 0);
                vv = __builtin_amdgcn_mfma_f32_16x16x32_bf16(afrag[mt][0], bv[sub][0], vv, 0, 0, 0);
                vv = __builtin_amdgcn_mfma_f32_16x16x32_bf16(afrag[mt][1], bv[sub][1], vv, 0, 0, 0);
                #pragma unroll
                for (int r = 0; r < 4; r++) {
                    float gv = g[r];
                    float sig = __builtin_amdgcn_rcpf(1.0f + __expf(-gv));
                    float hval = gv * sig * vv[r];
                    hbuf[(mt * 16 + quad * 4 + r) * 36 + sub * 16 + l15] = (__bf16)hval;
                }
            }
        }
        // ---- fc2 partial over k_h = np*32..np*32+31 ----
        #pragma unroll
        for (int mt = 0; mt < 2; mt++) {
            bf16x8 ah = *(const bf16x8*)&hbuf[(mt * 16 + l15) * 36 + quad * 8];
            #pragma unroll
            for (int dt = 0; dt < 4; dt++)
                oacc[mt][dt] = __builtin_amdgcn_mfma_f32_16x16x32_bf16(ah, bf[dt], oacc[mt][dt], 0, 0, 0);
        }
    }

    // ---- epilogue: += x residual (cache-hot), store fp32 (C-layout) ----
    #pragma unroll
    for (int mt = 0; mt < 2; mt++) {
        int r0 = w * 32 + mt * 16 + quad * 4;
        #pragma unroll
        for (int rg = 0; rg < 4; rg++) {
            size_t roff = row_base + (size_t)(r0 + rg) * DD;
            #pragma unroll
            for (int dt = 0; dt < 4; dt++) {
                int col = dt * 16 + l15;
                out[roff + col] = oacc[mt][dt][rg] + x[roff + col];
            }
        }
    }
}

// ---------------------------------------------------------------------------
extern "C" void kernel_launch(void* const* d_in, const int* in_sizes, int n_in,
                              void* d_out, int out_size, void* d_ws, size_t ws_size,
                              hipStream_t stream)
{
    const float* x     = (const float*)d_in[0];
    const float* s     = (const float*)d_in[1];
    const float* W_pg  = (const float*)d_in[2];
    const float* b_pg  = (const float*)d_in[3];
    const float* scale = (const float*)d_in[4];
    float* out = (float*)d_out;

    char* ws = (char*)d_ws;
    float*  params = (float*)ws;                                  // 12,582,912 B
    __bf16* WgT    = (__bf16*)(ws + 12582912);                    //  2,097,152 B
    __bf16* WvT    = (__bf16*)(ws + 14680064);                    //  2,097,152 B
    __bf16* WfT    = (__bf16*)(ws + 16777216);                    //  2,097,152 B

    k1_gemm<<<TOTAL / 64, 256, 0, stream>>>(s, W_pg, b_pg, params);
    k2_fc1<<<BB * 4, 256, 0, stream>>>(params, WgT, WvT);
    k2_fc2<<<BB * 2, 256, 0, stream>>>(params, WfT);
    k3_fused<<<BB * 32, 256, 0, stream>>>(x, scale, WgT, WvT, WfT, out);
}

// Round 3
// 440.836 us; speedup vs baseline: 1.0589x; 1.0367x over previous
//
#include <hip/hip_runtime.h>
#include <hip/hip_bf16.h>

// Problem constants
#define BB 64
#define NN 4096
#define DD 64
#define HH 256
#define SS 1024
#define TOTAL 49152          // 3*D*H
#define MAT_ELEMS 16384      // D*H

typedef __bf16 bf16x8 __attribute__((ext_vector_type(8)));
typedef float  f32x4  __attribute__((ext_vector_type(4)));

// ---------------------------------------------------------------------------
// K1: params[64][49152] = s[64][1024] @ W_pg[1024][49152] + b_pg
// Register-tiled fp32 vector GEMM with REGISTER PREFETCH of the next K-tile:
// global loads for k0+32 are issued right after the barrier, overlapping the
// 32-step FMA loop on tile k0. grid 768 (= 3 blocks/CU, whole grid resident).
// ---------------------------------------------------------------------------
__global__ __launch_bounds__(256, 4) void k1_gemm(
    const float* __restrict__ s, const float* __restrict__ W,
    const float* __restrict__ bias, float* __restrict__ params)
{
    const int n0 = blockIdx.x * 64;
    const int t  = threadIdx.x;
    const int tx = t & 15, ty = t >> 4;

    __shared__ float sA[64 * 36];   // s tile [m][kk]
    __shared__ float sB[32 * 68];   // W tile [kk][n]

    float acc[4][4] = {};

    // prefetch source pointers (two float4 each for A and B)
    const float* sp0 = &s[(size_t)(t >> 3) * SS + (t & 7) * 4];
    const float* sp1 = sp0 + (size_t)32 * SS;
    const float* wp0 = &W[(size_t)(t >> 4) * TOTAL + n0 + (t & 15) * 4];
    const float* wp1 = wp0 + (size_t)16 * TOTAL;

    float4 pA0 = *(const float4*)(sp0);
    float4 pA1 = *(const float4*)(sp1);
    float4 pB0 = *(const float4*)(wp0);
    float4 pB1 = *(const float4*)(wp1);

    for (int k0 = 0; k0 < SS; k0 += 32) {
        // store prefetched tile to LDS
        *(float4*)&sA[(t >> 3) * 36 + (t & 7) * 4]        = pA0;
        *(float4*)&sA[((t >> 3) + 32) * 36 + (t & 7) * 4] = pA1;
        *(float4*)&sB[(t >> 4) * 68 + (t & 15) * 4]        = pB0;
        *(float4*)&sB[((t >> 4) + 16) * 68 + (t & 15) * 4] = pB1;
        __syncthreads();
        // issue next tile's global loads NOW (consumed next iteration)
        if (k0 + 32 < SS) {
            pA0 = *(const float4*)(sp0 + k0 + 32);
            pA1 = *(const float4*)(sp1 + k0 + 32);
            pB0 = *(const float4*)(wp0 + (size_t)(k0 + 32) * TOTAL);
            pB1 = *(const float4*)(wp1 + (size_t)(k0 + 32) * TOTAL);
        }
        #pragma unroll
        for (int kk = 0; kk < 32; kk++) {
            float4 b = *(const float4*)&sB[kk * 68 + tx * 4];
            float a0 = sA[(ty * 4 + 0) * 36 + kk];
            float a1 = sA[(ty * 4 + 1) * 36 + kk];
            float a2 = sA[(ty * 4 + 2) * 36 + kk];
            float a3 = sA[(ty * 4 + 3) * 36 + kk];
            acc[0][0] += a0 * b.x; acc[0][1] += a0 * b.y; acc[0][2] += a0 * b.z; acc[0][3] += a0 * b.w;
            acc[1][0] += a1 * b.x; acc[1][1] += a1 * b.y; acc[1][2] += a1 * b.z; acc[1][3] += a1 * b.w;
            acc[2][0] += a2 * b.x; acc[2][1] += a2 * b.y; acc[2][2] += a2 * b.z; acc[2][3] += a2 * b.w;
            acc[3][0] += a3 * b.x; acc[3][1] += a3 * b.y; acc[3][2] += a3 * b.z; acc[3][3] += a3 * b.w;
        }
        __syncthreads();
    }

    #pragma unroll
    for (int r = 0; r < 4; r++) {
        int m = ty * 4 + r;
        int n = n0 + tx * 4;
        float4 bv = *(const float4*)&bias[n];
        float4 o;
        o.x = acc[r][0] + bv.x; o.y = acc[r][1] + bv.y;
        o.z = acc[r][2] + bv.z; o.w = acc[r][3] + bv.w;
        *(float4*)&params[(size_t)m * TOTAL + n] = o;
    }
}

// ---------------------------------------------------------------------------
// K2a: fc1 gate/value l2norm along D, write transposed bf16 WT[h][d].
// grid 256 (64 b x {g,v} x 2 h-halves), block 256.
// ---------------------------------------------------------------------------
__global__ __launch_bounds__(256) void k2_fc1(
    const float* __restrict__ params, __bf16* __restrict__ WgT, __bf16* __restrict__ WvT)
{
    const int b   = blockIdx.x >> 2;
    const int mat = (blockIdx.x >> 1) & 1;
    const int hh  = blockIdx.x & 1;
    const int t   = threadIdx.x;
    __shared__ float sh[64 * 130];     // [d][h-half 128], pad 130
    __shared__ float rnorm[128];

    const float* src = params + (size_t)b * TOTAL + mat * MAT_ELEMS + hh * 128;
    #pragma unroll
    for (int i = 0; i < 32; i++) {
        int idx = t + i * 256;          // idx = d*128 + h
        int d = idx >> 7, h = idx & 127;
        sh[d * 130 + h] = src[d * 256 + h];
    }
    __syncthreads();
    if (t < 128) {
        float sum = 0.f;
        #pragma unroll
        for (int d = 0; d < 64; d++) {
            float v = sh[d * 130 + t];
            sum += v * v;
        }
        rnorm[t] = 1.0f / fmaxf(sqrtf(sum), 1e-12f);
    }
    __syncthreads();
    __bf16* dst = (mat ? WvT : WgT) + (size_t)b * MAT_ELEMS;
    #pragma unroll
    for (int i = 0; i < 32; i++) {
        int idx = t + i * 256;          // idx = hl*64 + d
        int hl = idx >> 6, d = idx & 63;
        dst[(hh * 128 + hl) * 64 + d] = (__bf16)(sh[d * 130 + hl] * rnorm[hl]);
    }
}

// ---------------------------------------------------------------------------
// K2b: fc2 l2norm along H, write transposed bf16 WfT[d][h].
// grid 128 (64 b x 2 d-halves), block 256.
// ---------------------------------------------------------------------------
__global__ __launch_bounds__(256) void k2_fc2(
    const float* __restrict__ params, __bf16* __restrict__ WfT)
{
    const int b  = blockIdx.x >> 1;
    const int dh = blockIdx.x & 1;
    const int t  = threadIdx.x;
    __shared__ float sh[256 * 33];     // [h][d-half 32], pad 33
    __shared__ float psum[8 * 32];
    __shared__ float rnorm[32];

    const float* src = params + (size_t)b * TOTAL + 2 * MAT_ELEMS + dh * 32;
    #pragma unroll
    for (int i = 0; i < 32; i++) {
        int idx = t + i * 256;          // idx = h*32 + d
        int h = idx >> 5, d = idx & 31;
        sh[h * 33 + d] = src[h * 64 + d];
    }
    __syncthreads();
    {
        int d = t & 31, seg = t >> 5;
        float sum = 0.f;
        #pragma unroll
        for (int hi = 0; hi < 32; hi++) {
            float v = sh[(seg * 32 + hi) * 33 + d];
            sum += v * v;
        }
        psum[seg * 32 + d] = sum;
    }
    __syncthreads();
    if (t < 32) {
        float sum = 0.f;
        #pragma unroll
        for (int seg = 0; seg < 8; seg++) sum += psum[seg * 32 + t];
        rnorm[t] = 1.0f / fmaxf(sqrtf(sum), 1e-12f);
    }
    __syncthreads();
    __bf16* dst = WfT + (size_t)b * MAT_ELEMS;
    #pragma unroll
    for (int i = 0; i < 32; i++) {
        int idx = t + i * 256;          // idx = d*256 + h
        int d = idx >> 8, h = idx & 255;
        dst[(dh * 32 + d) * 256 + h] = (__bf16)(sh[h * 33 + d] * rnorm[d]);
    }
}

// ---------------------------------------------------------------------------
// K3: fused  xn = rmsnorm(x)*scale;  g = xn@Wg; v = xn@Wv; h = silu(g)*v;
//            out = h@Wf + x.
// grid 2048 (64 b x 32 row-blocks of 128 rows), block 256 = 4 waves, each wave
// owns 32 rows. RESTRUCTURED vs R2: per 128-h half, run 4 fc1 iterations
// (loads batched, MFMA, silu, ds_write ONLY — no LDS-read dependency), then
// one fc2 sweep reading the whole half from the wave-private h buffer. The
// ds_write->ds_read lgkmcnt chain now occurs 2x per wave instead of 8x, and
// fc1 iterations are pure load->MFMA->VALU->store chains the scheduler can
// overlap across 16 resident waves/CU. h buffer: [32][136] bf16 per wave
// (2-way-conflict-free, rows 16B-aligned), 34.8 KB/block -> 4 blocks/CU.
// NO __syncthreads anywhere.
// ---------------------------------------------------------------------------
__global__ __launch_bounds__(256, 4) void k3_fused(
    const float* __restrict__ x, const float* __restrict__ scale,
    const __bf16* __restrict__ WgT, const __bf16* __restrict__ WvT,
    const __bf16* __restrict__ WfT, float* __restrict__ out)
{
    const int b    = blockIdx.x >> 5;
    const int rb   = blockIdx.x & 31;
    const int t    = threadIdx.x;
    const int w    = t >> 6;
    const int lane = t & 63;
    const int l15  = lane & 15;
    const int quad = lane >> 4;

    __shared__ __bf16 h_sh[4 * 32 * 136];   // 34816 B: per-wave [32 rows][128h pad 136]

    const size_t row_base = ((size_t)b * NN + rb * 128) * DD;

    // per-lane scale slices for k = quad*8+j and 32+quad*8+j
    float sc[16];
    *(float4*)&sc[0]  = *(const float4*)&scale[quad * 8];
    *(float4*)&sc[4]  = *(const float4*)&scale[quad * 8 + 4];
    *(float4*)&sc[8]  = *(const float4*)&scale[32 + quad * 8];
    *(float4*)&sc[12] = *(const float4*)&scale[32 + quad * 8 + 4];

    // ---- phase 0: build A-fragments straight from global ----
    bf16x8 afrag[2][2];
    #pragma unroll
    for (int mt = 0; mt < 2; mt++) {
        int row = w * 32 + mt * 16 + l15;
        const float* xp = &x[row_base + (size_t)row * DD + quad * 8];
        float v[16];
        *(float4*)&v[0]  = *(const float4*)(xp);
        *(float4*)&v[4]  = *(const float4*)(xp + 4);
        *(float4*)&v[8]  = *(const float4*)(xp + 32);
        *(float4*)&v[12] = *(const float4*)(xp + 36);
        float ss = 0.f;
        #pragma unroll
        for (int j = 0; j < 16; j++) ss += v[j] * v[j];
        ss += __shfl_xor(ss, 16, 64);
        ss += __shfl_xor(ss, 32, 64);
        float rr = rsqrtf(ss * (1.0f / 64.0f) + 1e-6f);
        #pragma unroll
        for (int j = 0; j < 8; j++) {
            afrag[mt][0][j] = (__bf16)(v[j] * rr * sc[j]);
            afrag[mt][1][j] = (__bf16)(v[8 + j] * rr * sc[8 + j]);
        }
    }

    f32x4 oacc[2][4] = {};   // [mt][dt]
    const __bf16* wg_b = WgT + (size_t)b * MAT_ELEMS;
    const __bf16* wv_b = WvT + (size_t)b * MAT_ELEMS;
    const __bf16* wf_b = WfT + (size_t)b * MAT_ELEMS;
    __bf16* hbuf = &h_sh[w * 32 * 136];

    for (int half = 0; half < 2; half++) {
        // ================= fc1 phase: 4 np iterations, write-only LDS ======
        #pragma unroll
        for (int npl = 0; npl < 4; npl++) {
            const int np = half * 4 + npl;
            // batch-issue all 8 weight fragment loads
            bf16x8 bg[2][2], bv[2][2];
            #pragma unroll
            for (int sub = 0; sub < 2; sub++) {
                int nt = np * 2 + sub;
                const __bf16* gp = &wg_b[(nt * 16 + l15) * 64 + quad * 8];
                const __bf16* vp = &wv_b[(nt * 16 + l15) * 64 + quad * 8];
                bg[sub][0] = *(const bf16x8*)(gp);
                bg[sub][1] = *(const bf16x8*)(gp + 32);
                bv[sub][0] = *(const bf16x8*)(vp);
                bv[sub][1] = *(const bf16x8*)(vp + 32);
            }
            #pragma unroll
            for (int sub = 0; sub < 2; sub++) {
                #pragma unroll
                for (int mt = 0; mt < 2; mt++) {
                    f32x4 g = {0.f, 0.f, 0.f, 0.f}, vv = {0.f, 0.f, 0.f, 0.f};
                    g  = __builtin_amdgcn_mfma_f32_16x16x32_bf16(afrag[mt][0], bg[sub][0], g, 0, 0, 0);
                    g  = __builtin_amdgcn_mfma_f32_16x16x32_bf16(afrag[mt][1], bg[sub][1], g, 0, 0, 0);
                    vv = __builtin_amdgcn_mfma_f32_16x16x32_bf16(afrag[mt][0], bv[sub][0], vv, 0, 0, 0);
                    vv = __builtin_amdgcn_mfma_f32_16x16x32_bf16(afrag[mt][1], bv[sub][1], vv, 0, 0, 0);
                    #pragma unroll
                    for (int r = 0; r < 4; r++) {
                        float gv = g[r];
                        float sig = __builtin_amdgcn_rcpf(1.0f + __expf(-gv));
                        float hval = gv * sig * vv[r];
                        hbuf[(mt * 16 + quad * 4 + r) * 136 + npl * 32 + sub * 16 + l15] = (__bf16)hval;
                    }
                }
            }
        }
        // ================= fc2 phase: sweep the 128-h half =================
        #pragma unroll
        for (int kpl = 0; kpl < 4; kpl++) {
            const int kp = half * 4 + kpl;
            bf16x8 bf[4];
            #pragma unroll
            for (int dt = 0; dt < 4; dt++)
                bf[dt] = *(const bf16x8*)&wf_b[(dt * 16 + l15) * 256 + kp * 32 + quad * 8];
            #pragma unroll
            for (int mt = 0; mt < 2; mt++) {
                bf16x8 ah = *(const bf16x8*)&hbuf[(mt * 16 + l15) * 136 + kpl * 32 + quad * 8];
                #pragma unroll
                for (int dt = 0; dt < 4; dt++)
                    oacc[mt][dt] = __builtin_amdgcn_mfma_f32_16x16x32_bf16(ah, bf[dt], oacc[mt][dt], 0, 0, 0);
            }
        }
    }

    // ---- epilogue: += x residual (cache-hot), store fp32 (C-layout) ----
    #pragma unroll
    for (int mt = 0; mt < 2; mt++) {
        int r0 = w * 32 + mt * 16 + quad * 4;
        #pragma unroll
        for (int rg = 0; rg < 4; rg++) {
            size_t roff = row_base + (size_t)(r0 + rg) * DD;
            #pragma unroll
            for (int dt = 0; dt < 4; dt++) {
                int col = dt * 16 + l15;
                out[roff + col] = oacc[mt][dt][rg] + x[roff + col];
            }
        }
    }
}

// ---------------------------------------------------------------------------
extern "C" void kernel_launch(void* const* d_in, const int* in_sizes, int n_in,
                              void* d_out, int out_size, void* d_ws, size_t ws_size,
                              hipStream_t stream)
{
    const float* x     = (const float*)d_in[0];
    const float* s     = (const float*)d_in[1];
    const float* W_pg  = (const float*)d_in[2];
    const float* b_pg  = (const float*)d_in[3];
    const float* scale = (const float*)d_in[4];
    float* out = (float*)d_out;

    char* ws = (char*)d_ws;
    float*  params = (float*)ws;                                  // 12,582,912 B
    __bf16* WgT    = (__bf16*)(ws + 12582912);                    //  2,097,152 B
    __bf16* WvT    = (__bf16*)(ws + 14680064);                    //  2,097,152 B
    __bf16* WfT    = (__bf16*)(ws + 16777216);                    //  2,097,152 B

    k1_gemm<<<TOTAL / 64, 256, 0, stream>>>(s, W_pg, b_pg, params);
    k2_fc1<<<BB * 4, 256, 0, stream>>>(params, WgT, WvT);
    k2_fc2<<<BB * 2, 256, 0, stream>>>(params, WfT);
    k3_fused<<<BB * 32, 256, 0, stream>>>(x, scale, WgT, WvT, WfT, out);
}